// Round 3
// baseline (226.502 us; speedup 1.0000x reference)
//
#include <hip/hip_runtime.h>
#include <hip/hip_bf16.h>

#define QN 4096
#define CN 4096
#define DN 1024
#define EPSV 1e-6f

#define BM 128
#define BN 128
#define BK 64
#define TILE (BM * BK)          // 8192 bf16 elems = 16 KB per staged tile

#define MATSZ ((size_t)QN * DN)

using bf16x8 = __attribute__((ext_vector_type(8))) __bf16;
using f32x4  = __attribute__((ext_vector_type(4))) float;

static __device__ __forceinline__ unsigned short f2bf_rne(float x) {
  unsigned int u = __float_as_uint(x);
  unsigned int r = (u + 0x7FFFu + ((u >> 16) & 1u)) >> 16;
  return (unsigned short)r;
}
static __device__ __forceinline__ float bf2f(unsigned short h) {
  return __uint_as_float(((unsigned int)h) << 16);
}

// async global->LDS, 16B per lane; LDS dest is wave-uniform base + lane*16
static __device__ __forceinline__ void gload_lds16(const unsigned short* g, unsigned short* l) {
  __builtin_amdgcn_global_load_lds(
      (const __attribute__((address_space(1))) unsigned int*)g,
      (__attribute__((address_space(3))) unsigned int*)l, 16, 0, 0);
}

// ws16 layout (ushort elems): 0:t_rgb | 1:t_flow | 2:c_rgb | 3:c_flow (bf16-rounded)
// then norms (float): tn_r[QN], tn_f[QN], cn_r[CN], cn_f[CN]
// Norms are computed from the ROUNDED values so sq = ||a~||^2+||b~||^2-2 a~.b~
// is the exact squared distance of the perturbed vectors.

__global__ void prep_kernel(const float* __restrict__ tgt_r, const float* __restrict__ tgt_f,
                            const float* __restrict__ ctx_r, const float* __restrict__ ctx_f,
                            unsigned short* __restrict__ ws16, float* __restrict__ norms) {
  const int row = blockIdx.x;
  const int mat = blockIdx.y;
  const int t = threadIdx.x;
  const float* src; float eps;
  switch (mat) {
    case 0:  src = tgt_r; eps = EPSV; break;
    case 1:  src = tgt_f; eps = EPSV; break;
    case 2:  src = ctx_r; eps = 0.f;  break;
    default: src = ctx_f; eps = 0.f;  break;
  }
  unsigned short* hi = ws16 + (size_t)mat * MATSZ;
  float* nrm = norms + (size_t)mat * QN;
  const size_t base = (size_t)row * DN;
  float4 v = ((const float4*)(src + base))[t];
  float a[4] = {v.x + eps, v.y + eps, v.z + eps, v.w + eps};
  float ss = 0.f;
  unsigned short hh[4];
#pragma unroll
  for (int k = 0; k < 4; ++k) {
    hh[k] = f2bf_rne(a[k]);
    float f = bf2f(hh[k]);         // norm of the rounded value (consistency)
    ss += f * f;
  }
  ((ushort4*)(hi + base))[t] = make_ushort4(hh[0], hh[1], hh[2], hh[3]);

#pragma unroll
  for (int o = 32; o > 0; o >>= 1) ss += __shfl_down(ss, o);
  __shared__ float red[4];
  if ((t & 63) == 0) red[t >> 6] = ss;
  __syncthreads();
  if (t == 0) nrm[row] = red[0] + red[1] + red[2] + red[3];
}

// Single-matrix bf16 GEMM + distance/exp epilogue (m97 structure: 128x128 tile,
// 4 waves 2x2, wave = 64x64 via 4x4 frags of mfma_f32_16x16x32_bf16, BK=64,
// single-buffered LDS, 2 barriers per K-step).
// __launch_bounds__(256, 3): pin the m97 operating point (164 VGPR / 3
// blocks/CU). The cross-block wave overlap at 3 blocks/CU is what hides the
// vmcnt(0)-before-barrier drain (m114); at 2 blocks/CU (the old fused-dual
// kernel's regime) that drain goes unhidden and the structure runs at ~44%
// of its rate. Cap VGPR <= ~170 rather than risk a 171-256 allocation.
// LDS 16B-chunks are XOR-swizzled by (row&7) on the *source* address to break
// the all-rows-same-bank-phase of the 128 B row stride (both-sides-or-neither
// rule: linear gload_lds dest + inverse-swizzled source + swizzled read).
// ACCUM=false: out = w*exp(-d);  ACCUM=true: out += w*exp(-d)  (RMW, no race:
// exactly one thread owns each output element; the two gemm dispatches are
// sequential on the stream).
template <bool ACCUM>
__global__ __launch_bounds__(256, 3)
void gemm_kernel(const unsigned short* __restrict__ A,   // [QN, DN] bf16 (+eps)
                 const unsigned short* __restrict__ B,   // [CN, DN] bf16
                 const float* __restrict__ tn,           // ||A row||^2
                 const float* __restrict__ cn,           // ||B row||^2
                 const float* __restrict__ cw_num,       // weight numerator  (c_x)
                 const float* __restrict__ cw_oth,       // weight other term
                 float* __restrict__ out) {
  __shared__ unsigned short S[2 * TILE];   // A | B, each 128x64, swizzled

  const int t = threadIdx.x;
  const int lane = t & 63;
  const int wid = t >> 6;
  const int wr = wid >> 1;
  const int wc = wid & 1;
  const int row0 = blockIdx.y * BM;   // target rows
  const int col0 = blockIdx.x * BN;   // context cols

  f32x4 acc[4][4];
#pragma unroll
  for (int i = 0; i < 4; ++i)
#pragma unroll
    for (int j = 0; j < 4; ++j)
      acc[i][j] = (f32x4){0.f, 0.f, 0.f, 0.f};

  // staging: per call site the block covers 32 rows x 64 cols (4 KB) per matrix.
  // wave w, lane l -> LDS row w*8 + (l>>3), LDS chunk (l&7) (chunk = 8 bf16).
  // source global chunk = (l&7) ^ (l>>3)   [row&7 == l>>3 since w*8, it*32 are mult of 8]
  const int srw = lane >> 3;               // 0..7
  const int sch = (lane & 7) ^ srw;        // swizzled source chunk
  const size_t src_off = (size_t)(wid * 8 + srw) * DN + sch * 8;
  const size_t aoff = (size_t)row0 * DN + src_off;
  const size_t boff = (size_t)col0 * DN + src_off;
  unsigned short* ldsW = S + wid * 8 * BK; // + it*32*BK per call, lane*16B implicit

  const unsigned short* pA = A + aoff;
  const unsigned short* pB = B + boff;

  // fragment read offsets (bf16 elems, row stride BK=64), XOR-unswizzle:
  // row R = (wr|wc)*64 + i*16 + lr  ->  R&7 == lr&7 ; chunk c = lq + 4*ksub
  const int lr = lane & 15;
  const int lq = lane >> 4;
  const int sc0 = (lq ^ (lr & 7)) * 8;     // ksub=0 chunk offset (elems)
  int ra[4], rb[4];
#pragma unroll
  for (int i = 0; i < 4; ++i) {
    ra[i] = (wr * 64 + i * 16 + lr) * BK + sc0;
    rb[i] = (wc * 64 + i * 16 + lr) * BK + sc0;
  }
  // ksub=1: chunk = (lq+4)^(lr&7) = (lq^(lr&7)) ^ 4  ->  offset ^ 32 elems
#define KS1(x) ((x) ^ 32)

  for (int kc = 0; kc < DN / BK; ++kc) {
    const int k = kc * BK;
    __syncthreads();   // previous chunk fully consumed
#pragma unroll
    for (int it = 0; it < 4; ++it) {
      const size_t g = (size_t)it * 32 * DN + k;
      unsigned short* l = ldsW + it * 32 * BK;
      gload_lds16(pA + g, l + 0 * TILE);
      gload_lds16(pB + g, l + 1 * TILE);
    }
    __syncthreads();   // vmcnt drained -> LDS valid

#pragma unroll
    for (int ksub = 0; ksub < 2; ++ksub) {
      bf16x8 ar[4], br[4];
#pragma unroll
      for (int i = 0; i < 4; ++i) {
        const int oa = ksub ? KS1(ra[i]) : ra[i];
        const int ob = ksub ? KS1(rb[i]) : rb[i];
        ar[i] = *(const bf16x8*)(S + oa);
        br[i] = *(const bf16x8*)(S + TILE + ob);
      }
#pragma unroll
      for (int i = 0; i < 4; ++i)
#pragma unroll
        for (int j = 0; j < 4; ++j)
          acc[i][j] = __builtin_amdgcn_mfma_f32_16x16x32_bf16(ar[i], br[j], acc[i][j], 0, 0, 0);
    }
  }

  // epilogue: sq = ||t||^2 + ||c||^2 - 2*dot ; e = w*exp(-sqrt(max(sq,0)))
  // C/D mapping (16x16x32 bf16): col = lane&15, row = (lane>>4)*4 + reg
  float cnv[4];
  int ccv[4];
#pragma unroll
  for (int j = 0; j < 4; ++j) {
    ccv[j] = col0 + wc * 64 + j * 16 + lr;
    cnv[j] = cn[ccv[j]];
  }

#pragma unroll
  for (int i = 0; i < 4; ++i) {
#pragma unroll
    for (int r = 0; r < 4; ++r) {
      const int tq = row0 + wr * 64 + i * 16 + lq * 4 + r;
      const float tnq = tn[tq];
      const float num = cw_num[tq], oth = cw_oth[tq];
      const float wgt = num / (num + oth);
      float* orow = out + (size_t)tq * CN;
#pragma unroll
      for (int j = 0; j < 4; ++j) {
        const float sq = tnq + cnv[j] - 2.f * acc[i][j][r];
        const float d = sqrtf(fmaxf(sq, 0.f));
        const float e = wgt * __expf(-d);
        if (ACCUM) {
          orow[ccv[j]] += e;
        } else {
          orow[ccv[j]] = e;
        }
      }
    }
  }
}

// Per-row sum + normalize, in place. Deterministic (no atomics).
__global__ void norm_kernel(float* __restrict__ out) {
  const int row = blockIdx.x;
  const int t = threadIdx.x;
  float4* p = (float4*)(out + (size_t)row * CN);
  float4 v[4];
  float s = 0.f;
#pragma unroll
  for (int i = 0; i < 4; ++i) {
    v[i] = p[t + 256 * i];
    s += v[i].x + v[i].y + v[i].z + v[i].w;
  }
#pragma unroll
  for (int o = 32; o > 0; o >>= 1) s += __shfl_down(s, o);
  __shared__ float red[4];
  if ((t & 63) == 0) red[t >> 6] = s;
  __syncthreads();
  const float inv = 1.f / (red[0] + red[1] + red[2] + red[3]);
#pragma unroll
  for (int i = 0; i < 4; ++i) {
    v[i].x *= inv; v[i].y *= inv; v[i].z *= inv; v[i].w *= inv;
    p[t + 256 * i] = v[i];
  }
}

extern "C" void kernel_launch(void* const* d_in, const int* in_sizes, int n_in,
                              void* d_out, int out_size, void* d_ws, size_t ws_size,
                              hipStream_t stream) {
  const float* ctx_r = (const float*)d_in[0];
  const float* ctx_f = (const float*)d_in[1];
  const float* tgt_r = (const float*)d_in[2];
  const float* tgt_f = (const float*)d_in[3];
  const float* c_r   = (const float*)d_in[4];
  const float* c_f   = (const float*)d_in[5];
  float* out = (float*)d_out;
  unsigned short* ws16 = (unsigned short*)d_ws;
  float* norms = (float*)(ws16 + 4 * MATSZ);

  prep_kernel<<<dim3(QN, 4), 256, 0, stream>>>(tgt_r, tgt_f, ctx_r, ctx_f, ws16, norms);
  // rgb term: out = w_r * exp(-d_rgb)
  gemm_kernel<false><<<dim3(CN / BN, QN / BM), 256, 0, stream>>>(
      ws16 + 0 * MATSZ, ws16 + 2 * MATSZ, norms, norms + 2 * QN, c_r, c_f, out);
  // flow term: out += w_f * exp(-d_flow)
  gemm_kernel<true><<<dim3(CN / BN, QN / BM), 256, 0, stream>>>(
      ws16 + 1 * MATSZ, ws16 + 3 * MATSZ, norms + QN, norms + 3 * QN, c_f, c_r, out);
  norm_kernel<<<QN, 256, 0, stream>>>(out);
}